// Round 8
// baseline (625.825 us; speedup 1.0000x reference)
//
#include <hip/hip_runtime.h>
#include <hip/hip_bf16.h>

#define N_VOCAB 50257
#define NB      393     // n-block columns
#define N_PAD   50304   // 393 * 128
#define D_K     1024
#define M_ROWS  2048
#define GEMM_BLOCKS (NB * 16)       // 6288 = 8 * 786
#define PER_XCD     (GEMM_BLOCKS/8) // 786

typedef __attribute__((ext_vector_type(4))) int i32x4;

__device__ inline void async_copy16(const void* g, void* l) {
  auto* gp = (const __attribute__((address_space(1))) unsigned int*)g;
  auto* lp = (__attribute__((address_space(3))) unsigned int*)l;
  __builtin_amdgcn_global_load_lds(gp, lp, 16, 0, 0);
}

__device__ inline signed char qint(float v, float s) {
  float q = fminf(fmaxf(rintf(v / s), -8.f), 7.f);
  return (signed char)(int)q;
}

// ---------------- fused absmax (x -> amax[0], W -> amax[1]) ----------------
__global__ void absmax2_kernel(const float4* __restrict__ x, int nx4,
                               const float4* __restrict__ Wp, int nw4,
                               unsigned* __restrict__ amax) {
  const bool isx = blockIdx.x < 512;
  const float4* p = isx ? x : Wp;
  const int n4 = isx ? nx4 : nw4;
  const int b0 = isx ? blockIdx.x : blockIdx.x - 512;
  const int nb = isx ? 512 : (gridDim.x - 512);
  float m = 0.f;
  for (int i = b0 * blockDim.x + threadIdx.x; i < n4; i += nb * blockDim.x) {
    float4 v = p[i];
    m = fmaxf(m, fmaxf(fmaxf(fabsf(v.x), fabsf(v.y)),
                       fmaxf(fabsf(v.z), fabsf(v.w))));
  }
#pragma unroll
  for (int off = 32; off; off >>= 1) m = fmaxf(m, __shfl_xor(m, off));
  __shared__ float red[4];
  int tid = threadIdx.x;
  if ((tid & 63) == 0) red[tid >> 6] = m;
  __syncthreads();
  if (tid == 0) {
    m = fmaxf(fmaxf(red[0], red[1]), fmaxf(red[2], red[3]));
    atomicMax(&amax[isx ? 0 : 1], __float_as_uint(m));
  }
}

// ---------------- fused quantize x, W, bias ----------------
__global__ void quant_kernel(const float4* __restrict__ x,
                             const float4* __restrict__ Wp,
                             const float* __restrict__ b,
                             char4* __restrict__ qx, char4* __restrict__ qw,
                             float* __restrict__ bq,
                             const unsigned* __restrict__ amax) {
  const int bid = blockIdx.x;
  const int tid = threadIdx.x;
  const int nw4 = (N_VOCAB * D_K) / 4;
  if (bid < 2048) {
    int i = bid * 256 + tid;
    float s = __uint_as_float(amax[0]) * (1.0f / 7.0f);
    float4 v = x[i];
    char4 q;
    q.x = qint(v.x, s); q.y = qint(v.y, s);
    q.z = qint(v.z, s); q.w = qint(v.w, s);
    qx[i] = q;
  } else if (bid < 2048 + 50304) {
    int i = (bid - 2048) * 256 + tid;
    char4 q = {0, 0, 0, 0};
    if (i < nw4) {
      float s = __uint_as_float(amax[1]) * (1.0f / 7.0f);
      float4 v = Wp[i];
      q.x = qint(v.x, s); q.y = qint(v.y, s);
      q.z = qint(v.z, s); q.w = qint(v.w, s);
    }
    qw[i] = q;
  } else {
    int i = (bid - (2048 + 50304)) * 256 + tid;
    if (i < N_PAD) {
      float v = 0.f;
      if (i < N_VOCAB) {
        float sb = (__uint_as_float(amax[0]) * (1.0f / 7.0f)) *
                   (__uint_as_float(amax[1]) * (1.0f / 7.0f));
        v = rintf(b[i] / sb) * sb;
      }
      bq[i] = v;
    }
  }
}

// ---------------- int8 GEMM + fused softmax partials ----------------
// 128x128 tile, 4 waves (2x2 of 64x64), BK=64. 4-PHASE schedule per K-step
// (phase = output quadrant): {4 ds_read_b128 | 1 global_load_lds (tile kt+2)
// -> s_barrier -> lgkmcnt(0) -> setprio(1) 4 MFMA setprio(0) -> s_barrier}.
// A and B in 3-slot rings (48 KB, 3 blocks/CU); step-boundary wait is
// counted vmcnt(4) - kt+2's 4 loads stay in flight, never drained mid-loop.
// 8-start XOR swizzle (0 conflicts, verified R5). mfma_i32_16x16x64_i8.
// XCD-bijective grid; reductions overlay dead sB after explicit barrier.
__global__ __launch_bounds__(256, 3) void gemm_kernel(
    const signed char* __restrict__ qx,   // [2048][1024]
    const signed char* __restrict__ qw,   // [50304][1024]
    const float* __restrict__ bq,         // [50304]
    const unsigned* __restrict__ amax,
    float* __restrict__ outp,             // [2048][50257]
    float* __restrict__ pmax,             // [2048][NB]
    float* __restrict__ psum)             // [2048][NB]
{
  constexpr int BK = 64;
  constexpr int NT = D_K / BK;  // 16
  __shared__ __align__(16) signed char sA[3][128 * BK];  // 24 KB
  __shared__ __align__(16) signed char sB[3][128 * BK];  // 24 KB

  const int tid = threadIdx.x;
  const int l = tid & 63;
  const int w = tid >> 6;
  const int wr = w >> 1, wc = w & 1;

  const int bid = blockIdx.x;
  const int vb = (bid & 7) * PER_XCD + (bid >> 3);
  const int nb = vb >> 4;          // 0..392
  const int m0 = (vb & 15) * 128;
  const int n0 = nb * 128;

  const float sx = __uint_as_float(amax[0]) * (1.0f / 7.0f);
  const float sw = __uint_as_float(amax[1]) * (1.0f / 7.0f);
  const float scale = sx * sw;

  i32x4 acc[4][4] = {};

  // staging: chunk = 16 rows x 64B, lane l -> row c*16+(l>>2); global source
  // k-slot pre-swizzled (slot ^ ((row>>1)&3)), LDS dest linear.
  const int srow = l >> 2;
  const int scol = ((l & 3) ^ ((l >> 3) & 3)) * 16;

  auto stA = [&](int buf, int kt, int i) {
    int c = w * 2 + i;
    int row = c * 16 + srow;
    async_copy16(qx + (size_t)(m0 + row) * D_K + kt * BK + scol,
                 &sA[buf][c * 1024]);
  };
  auto stB = [&](int buf, int kt, int i) {
    int c = w * 2 + i;
    int row = c * 16 + srow;
    async_copy16(qw + (size_t)(n0 + row) * D_K + kt * BK + scol,
                 &sB[buf][c * 1024]);
  };

  // prologue: tiles 0 and 1 fully issued (A,A,B,B order per tile);
  // wait tile 0 (4 oldest) done, tile 1's 4 stay outstanding.
  stA(0, 0, 0); stA(0, 0, 1); stB(0, 0, 0); stB(0, 0, 1);
  stA(1, 1, 0); stA(1, 1, 1); stB(1, 1, 0); stB(1, 1, 1);
  asm volatile("s_waitcnt vmcnt(4)" ::: "memory");
  __builtin_amdgcn_s_barrier();
  __builtin_amdgcn_sched_barrier(0);

#pragma unroll
  for (int kt = 0; kt < NT; ++kt) {
    const int cur = kt % 3;
    const int nx2 = (kt + 2) % 3;
    const bool pf = (kt + 2 < NT);

#pragma unroll
    for (int q = 0; q < 4; ++q) {
      const int mi2 = (q >> 1) * 2;  // 0 or 2
      const int ni2 = (q & 1) * 2;   // 0 or 2

      i32x4 a0, a1, b0, b1;
      {
        int row0 = wr * 64 + (mi2 + 0) * 16 + (l & 15);
        int row1 = wr * 64 + (mi2 + 1) * 16 + (l & 15);
        int k0 = ((l >> 4) ^ ((row0 >> 1) & 3)) * 16;
        int k1 = ((l >> 4) ^ ((row1 >> 1) & 3)) * 16;
        a0 = *(const i32x4*)&sA[cur][row0 * BK + k0];
        a1 = *(const i32x4*)&sA[cur][row1 * BK + k1];
      }
      {
        int row0 = wc * 64 + (ni2 + 0) * 16 + (l & 15);
        int row1 = wc * 64 + (ni2 + 1) * 16 + (l & 15);
        int k0 = ((l >> 4) ^ ((row0 >> 1) & 3)) * 16;
        int k1 = ((l >> 4) ^ ((row1 >> 1) & 3)) * 16;
        b0 = *(const i32x4*)&sB[cur][row0 * BK + k0];
        b1 = *(const i32x4*)&sB[cur][row1 * BK + k1];
      }

      // one prefetch load per phase, A,A,B,B order (FIFO-consistent)
      if (pf) {
        if (q == 0) stA(nx2, kt + 2, 0);
        if (q == 1) stA(nx2, kt + 2, 1);
        if (q == 2) stB(nx2, kt + 2, 0);
        if (q == 3) stB(nx2, kt + 2, 1);
      }

      __builtin_amdgcn_s_barrier();
      asm volatile("s_waitcnt lgkmcnt(0)" ::: "memory");
      __builtin_amdgcn_sched_barrier(0);
      __builtin_amdgcn_s_setprio(1);
      acc[mi2 + 0][ni2 + 0] = __builtin_amdgcn_mfma_i32_16x16x64_i8(
          a0, b0, acc[mi2 + 0][ni2 + 0], 0, 0, 0);
      acc[mi2 + 0][ni2 + 1] = __builtin_amdgcn_mfma_i32_16x16x64_i8(
          a0, b1, acc[mi2 + 0][ni2 + 1], 0, 0, 0);
      acc[mi2 + 1][ni2 + 0] = __builtin_amdgcn_mfma_i32_16x16x64_i8(
          a1, b0, acc[mi2 + 1][ni2 + 0], 0, 0, 0);
      acc[mi2 + 1][ni2 + 1] = __builtin_amdgcn_mfma_i32_16x16x64_i8(
          a1, b1, acc[mi2 + 1][ni2 + 1], 0, 0, 0);
      __builtin_amdgcn_s_setprio(0);

      if (q == 3) {
        if (kt + 1 < NT) {
          // kt+1's 4 loads retired; kt+2's 4 (if any) stay in flight
          if (pf)
            asm volatile("s_waitcnt vmcnt(4)" ::: "memory");
          else
            asm volatile("s_waitcnt vmcnt(0)" ::: "memory");
          __builtin_amdgcn_s_barrier();
          __builtin_amdgcn_sched_barrier(0);
        }
      } else {
        __builtin_amdgcn_s_barrier();
        __builtin_amdgcn_sched_barrier(0);
      }
    }
  }

  // ---- scale + bias ----
  bool valid[4];
  float bb[4];
#pragma unroll
  for (int ni = 0; ni < 4; ++ni) {
    int col = n0 + wc * 64 + ni * 16 + (l & 15);
    valid[ni] = (col < N_VOCAB);
    bb[ni] = valid[ni] ? bq[col] : 0.f;
  }
  float lg[4][4][4];
#pragma unroll
  for (int mi = 0; mi < 4; ++mi)
#pragma unroll
    for (int ni = 0; ni < 4; ++ni)
#pragma unroll
      for (int r = 0; r < 4; ++r)
        lg[mi][ni][r] = (float)acc[mi][ni][r] * scale + bb[ni];

  // ---- fused softmax partials (overlay dead sB; barrier first) ----
  __syncthreads();  // all waves done reading LDS before overlay writes
  float* redMax = (float*)&sB[0][0];  // [128][2]
  float* redSum = redMax + 256;       // [128][2]

  float rmax[4][4];
#pragma unroll
  for (int mi = 0; mi < 4; ++mi)
#pragma unroll
    for (int r = 0; r < 4; ++r) {
      float mval = -3.4e38f;
#pragma unroll
      for (int ni = 0; ni < 4; ++ni)
        if (valid[ni]) mval = fmaxf(mval, lg[mi][ni][r]);
#pragma unroll
      for (int off = 1; off < 16; off <<= 1)
        mval = fmaxf(mval, __shfl_xor(mval, off));
      rmax[mi][r] = mval;
      if ((l & 15) == 0)
        redMax[(wr * 64 + mi * 16 + (l >> 4) * 4 + r) * 2 + wc] = mval;
    }
  __syncthreads();

#pragma unroll
  for (int mi = 0; mi < 4; ++mi)
#pragma unroll
    for (int r = 0; r < 4; ++r) {
      int rl = wr * 64 + mi * 16 + (l >> 4) * 4 + r;
      float gmax = fmaxf(redMax[rl * 2 + 0], redMax[rl * 2 + 1]);
      float s = 0.f;
#pragma unroll
      for (int ni = 0; ni < 4; ++ni)
        if (valid[ni]) s += __expf(lg[mi][ni][r] - gmax);
#pragma unroll
      for (int off = 1; off < 16; off <<= 1)
        s += __shfl_xor(s, off);
      if ((l & 15) == 0) redSum[rl * 2 + wc] = s;
      rmax[mi][r] = gmax;
    }
  __syncthreads();

  if (wc == 0 && (l & 15) == 0) {
#pragma unroll
    for (int mi = 0; mi < 4; ++mi)
#pragma unroll
      for (int r = 0; r < 4; ++r) {
        int rl = wr * 64 + mi * 16 + (l >> 4) * 4 + r;
        int rowg = m0 + rl;
        pmax[(size_t)rowg * NB + nb] = rmax[mi][r];
        psum[(size_t)rowg * NB + nb] = redSum[rl * 2 + 0] + redSum[rl * 2 + 1];
      }
  }

  // ---- direct logit store, row-grouped so L2 merges a row's 256B run ----
#pragma unroll
  for (int mi = 0; mi < 4; ++mi)
#pragma unroll
    for (int r = 0; r < 4; ++r) {
      int rowg = m0 + wr * 64 + mi * 16 + (l >> 4) * 4 + r;
      size_t rb = (size_t)rowg * N_VOCAB;
#pragma unroll
      for (int ni = 0; ni < 4; ++ni) {
        if (valid[ni]) {
          int col = n0 + wc * 64 + ni * 16 + (l & 15);
          outp[rb + col] = lg[mi][ni][r];
        }
      }
    }
}

// ---------------- merged: per-row logZ + subtract (one kernel) ----------------
__global__ __launch_bounds__(256) void logz_sub_kernel(
    const float* __restrict__ pmax, const float* __restrict__ psum,
    float* __restrict__ out) {
  const int row = blockIdx.x;
  const float* pm = pmax + (size_t)row * NB;
  const float* ps = psum + (size_t)row * NB;
  const int tid = threadIdx.x;
  __shared__ float red[9];

  float m = -3.4e38f;
  for (int i = tid; i < NB; i += 256) m = fmaxf(m, pm[i]);
#pragma unroll
  for (int off = 32; off; off >>= 1) m = fmaxf(m, __shfl_xor(m, off));
  if ((tid & 63) == 0) red[tid >> 6] = m;
  __syncthreads();
  m = fmaxf(fmaxf(red[0], red[1]), fmaxf(red[2], red[3]));

  float s = 0.f;
  for (int i = tid; i < NB; i += 256) s += ps[i] * __expf(pm[i] - m);
#pragma unroll
  for (int off = 32; off; off >>= 1) s += __shfl_xor(s, off);
  if ((tid & 63) == 0) red[4 + (tid >> 6)] = s;
  __syncthreads();
  if (tid == 0) {
    s = red[4] + red[5] + red[6] + red[7];
    red[8] = m + __logf(s);
  }
  __syncthreads();
  const float lz = red[8];

  // subtract in place, aligned float4 body
  const size_t base = (size_t)row * N_VOCAB;
  const int a = (4 - (row & 3)) & 3;  // base mod 4 floats == row mod 4
  if (tid < a) out[base + tid] -= lz;
  const int n4 = (N_VOCAB - a) >> 2;
  float4* p = (float4*)(out + base + a);
  for (int i = tid; i < n4; i += 256) {
    float4 v = p[i];
    v.x -= lz; v.y -= lz; v.z -= lz; v.w -= lz;
    p[i] = v;
  }
  const int done = a + n4 * 4;
  if (tid < N_VOCAB - done) out[base + done + tid] -= lz;
}

extern "C" void kernel_launch(void* const* d_in, const int* in_sizes, int n_in,
                              void* d_out, int out_size, void* d_ws,
                              size_t ws_size, hipStream_t stream) {
  const float* x = (const float*)d_in[0];
  const float* W = (const float*)d_in[1];
  const float* b = (const float*)d_in[2];
  float* out = (float*)d_out;

  char* ws = (char*)d_ws;
  unsigned* amax = (unsigned*)ws;                       // 8 B
  float* bq = (float*)(ws + 4096);                      // 201 KB
  float* pmax = (float*)(ws + (2ull << 20));            // 3.22 MB
  float* psum = (float*)(ws + (6ull << 20));            // 3.22 MB
  signed char* qx = (signed char*)(ws + (10ull << 20)); // 2 MB
  signed char* qw = (signed char*)(ws + (14ull << 20)); // 51.5 MB

  hipMemsetAsync(amax, 0, 8, stream);

  const int nx4 = (M_ROWS * D_K) / 4;   // 524288
  const int nw4 = (N_VOCAB * D_K) / 4;  // 12865792

  absmax2_kernel<<<2560, 256, 0, stream>>>((const float4*)x, nx4,
                                           (const float4*)W, nw4, amax);

  quant_kernel<<<2048 + 50304 + 197, 256, 0, stream>>>(
      (const float4*)x, (const float4*)W, b, (char4*)qx, (char4*)qw, bq, amax);

  gemm_kernel<<<GEMM_BLOCKS, 256, 0, stream>>>(qx, qw, bq, amax, out, pmax,
                                               psum);

  logz_sub_kernel<<<M_ROWS, 256, 0, stream>>>(pmax, psum, out);
}

// Round 9
// 615.460 us; speedup vs baseline: 1.0168x; 1.0168x over previous
//
#include <hip/hip_runtime.h>
#include <hip/hip_bf16.h>

#define N_VOCAB 50257
#define NBC     197     // n-block columns (256 wide)
#define N_PAD   50432   // 197 * 256
#define D_K     1024
#define M_ROWS  2048
#define GEMM_BLOCKS (NBC * 8)   // 1576 = 8 XCDs * 197

typedef __attribute__((ext_vector_type(4))) int i32x4;

__device__ inline void async_copy16(const void* g, void* l) {
  auto* gp = (const __attribute__((address_space(1))) unsigned int*)g;
  auto* lp = (__attribute__((address_space(3))) unsigned int*)l;
  __builtin_amdgcn_global_load_lds(gp, lp, 16, 0, 0);
}

__device__ inline signed char qint(float v, float s) {
  float q = fminf(fmaxf(rintf(v / s), -8.f), 7.f);
  return (signed char)(int)q;
}

// ---------------- fused absmax (x -> amax[0], W -> amax[1]) ----------------
__global__ void absmax2_kernel(const float4* __restrict__ x, int nx4,
                               const float4* __restrict__ Wp, int nw4,
                               unsigned* __restrict__ amax) {
  const bool isx = blockIdx.x < 512;
  const float4* p = isx ? x : Wp;
  const int n4 = isx ? nx4 : nw4;
  const int b0 = isx ? blockIdx.x : blockIdx.x - 512;
  const int nb = isx ? 512 : (gridDim.x - 512);
  float m = 0.f;
  for (int i = b0 * blockDim.x + threadIdx.x; i < n4; i += nb * blockDim.x) {
    float4 v = p[i];
    m = fmaxf(m, fmaxf(fmaxf(fabsf(v.x), fabsf(v.y)),
                       fmaxf(fabsf(v.z), fabsf(v.w))));
  }
#pragma unroll
  for (int off = 32; off; off >>= 1) m = fmaxf(m, __shfl_xor(m, off));
  __shared__ float red[4];
  int tid = threadIdx.x;
  if ((tid & 63) == 0) red[tid >> 6] = m;
  __syncthreads();
  if (tid == 0) {
    m = fmaxf(fmaxf(red[0], red[1]), fmaxf(red[2], red[3]));
    atomicMax(&amax[isx ? 0 : 1], __float_as_uint(m));
  }
}

// ---------------- fused quantize x, W, bias ----------------
__global__ void quant_kernel(const float4* __restrict__ x,
                             const float4* __restrict__ Wp,
                             const float* __restrict__ b,
                             char4* __restrict__ qx, char4* __restrict__ qw,
                             float* __restrict__ bq,
                             const unsigned* __restrict__ amax) {
  const int bid = blockIdx.x;
  const int tid = threadIdx.x;
  const int nw4 = (N_VOCAB * D_K) / 4;
  if (bid < 2048) {
    int i = bid * 256 + tid;
    float s = __uint_as_float(amax[0]) * (1.0f / 7.0f);
    float4 v = x[i];
    char4 q;
    q.x = qint(v.x, s); q.y = qint(v.y, s);
    q.z = qint(v.z, s); q.w = qint(v.w, s);
    qx[i] = q;
  } else if (bid < 2048 + 50432) {
    int i = (bid - 2048) * 256 + tid;
    char4 q = {0, 0, 0, 0};
    if (i < nw4) {
      float s = __uint_as_float(amax[1]) * (1.0f / 7.0f);
      float4 v = Wp[i];
      q.x = qint(v.x, s); q.y = qint(v.y, s);
      q.z = qint(v.z, s); q.w = qint(v.w, s);
    }
    qw[i] = q;
  } else {
    int i = (bid - (2048 + 50432)) * 256 + tid;
    if (i < N_PAD) {
      float v = 0.f;
      if (i < N_VOCAB) {
        float sb = (__uint_as_float(amax[0]) * (1.0f / 7.0f)) *
                   (__uint_as_float(amax[1]) * (1.0f / 7.0f));
        v = rintf(b[i] / sb) * sb;
      }
      bq[i] = v;
    }
  }
}

// ---------------- int8 GEMM, m201-style 256x256 8-wave phase schedule ------
// 256x256 tile, 512 threads / 8 waves (2M x 4N), per-wave 128x64 output,
// BK=64 bytes, NT=16 K-tiles. A and B in 3-slot LDS rings (96 KB total,
// 1 block/CU, 2 waves/SIMD = m201 occupancy). Prefetch 2 K-tiles ahead;
// counted vmcnt(4) at K-tile boundaries (next-next tile's 4 loads stay in
// flight; never drained mid-loop). 2 phases per K-tile, 16 MFMA per phase:
// {ds_read subtile | 2 stage issues -> s_barrier -> lgkmcnt(0) ->
//  setprio(1) 16 MFMA setprio(0) -> s_barrier}. 8-start XOR swizzle
// (0 conflicts, verified R5). XCD-bijective grid (1576 = 8*197).
__global__ __launch_bounds__(512, 2) void gemm_kernel(
    const signed char* __restrict__ qx,   // [2048][1024]
    const signed char* __restrict__ qw,   // [50432][1024]
    const float* __restrict__ bq,         // [50432]
    const unsigned* __restrict__ amax,
    float* __restrict__ outp,             // [2048][50257]
    float* __restrict__ pmax,             // [2048][NBC]
    float* __restrict__ psum)             // [2048][NBC]
{
  constexpr int BK = 64;
  constexpr int NT = D_K / BK;  // 16
  __shared__ __align__(16) signed char sA[3][256 * BK];  // 48 KB
  __shared__ __align__(16) signed char sB[3][256 * BK];  // 48 KB

  const int tid = threadIdx.x;
  const int l = tid & 63;
  const int w = tid >> 6;   // 0..7
  const int wr = w >> 2;    // 0..1  (128 rows each)
  const int wc = w & 3;     // 0..3  (64 cols each)

  const int bid = blockIdx.x;
  const int vb = (bid & 7) * NBC + (bid >> 3);
  const int nb = vb >> 3;          // 0..196
  const int m0 = (vb & 7) * 256;
  const int n0 = nb * 256;

  const float sx = __uint_as_float(amax[0]) * (1.0f / 7.0f);
  const float sw = __uint_as_float(amax[1]) * (1.0f / 7.0f);
  const float scale = sx * sw;

  i32x4 acc[8][4] = {};

  // staging: one load-instruction = 512 thr x 16B = 128 rows x 64B half-tile.
  // lane -> row h*128 + w*16 + (l>>2); source k-slot pre-swizzled
  // (slot ^ ((row>>1)&3) = (l&3)^((l>>3)&3)); LDS dest linear.
  const int scol = ((l & 3) ^ ((l >> 3) & 3)) * 16;

  auto stA = [&](int buf, int kt, int h) {
    int row = h * 128 + w * 16 + (l >> 2);
    async_copy16(qx + (size_t)(m0 + row) * D_K + kt * BK + scol,
                 &sA[buf][(h * 128 + w * 16) * BK]);
  };
  auto stB = [&](int buf, int kt, int h) {
    int row = h * 128 + w * 16 + (l >> 2);
    async_copy16(qw + (size_t)(n0 + row) * D_K + kt * BK + scol,
                 &sB[buf][(h * 128 + w * 16) * BK]);
  };

  // prologue: tiles 0,1 fully issued (4 loads each); tile 0 ready, tile 1's
  // 4 loads stay outstanding.
  stA(0, 0, 0); stA(0, 0, 1); stB(0, 0, 0); stB(0, 0, 1);
  stA(1, 1, 0); stA(1, 1, 1); stB(1, 1, 0); stB(1, 1, 1);
  asm volatile("s_waitcnt vmcnt(4)" ::: "memory");
  __builtin_amdgcn_s_barrier();
  __builtin_amdgcn_sched_barrier(0);

  int cur = 0;
  for (int kt = 0; kt < NT; ++kt) {
    int nxt = cur + 2; if (nxt >= 3) nxt -= 3;
    const bool pf = (kt + 2 < NT);

    // ---- phase 0: B frags + A frags 0-3, stage A(kt+2), MFMA mi 0-3 ----
    i32x4 bfr[4], af[4];
#pragma unroll
    for (int ni = 0; ni < 4; ++ni) {
      int row = wc * 64 + ni * 16 + (l & 15);
      int kb = ((l >> 4) ^ ((row >> 1) & 3)) * 16;
      bfr[ni] = *(const i32x4*)&sB[cur][row * BK + kb];
    }
#pragma unroll
    for (int mi = 0; mi < 4; ++mi) {
      int row = wr * 128 + mi * 16 + (l & 15);
      int kb = ((l >> 4) ^ ((row >> 1) & 3)) * 16;
      af[mi] = *(const i32x4*)&sA[cur][row * BK + kb];
    }
    if (pf) { stA(nxt, kt + 2, 0); stA(nxt, kt + 2, 1); }

    __builtin_amdgcn_s_barrier();
    asm volatile("s_waitcnt lgkmcnt(0)" ::: "memory");
    __builtin_amdgcn_sched_barrier(0);
    __builtin_amdgcn_s_setprio(1);
#pragma unroll
    for (int mi = 0; mi < 4; ++mi)
#pragma unroll
      for (int ni = 0; ni < 4; ++ni)
        acc[mi][ni] = __builtin_amdgcn_mfma_i32_16x16x64_i8(
            af[mi], bfr[ni], acc[mi][ni], 0, 0, 0);
    __builtin_amdgcn_s_setprio(0);
    __builtin_amdgcn_sched_barrier(0);
    __builtin_amdgcn_s_barrier();
    __builtin_amdgcn_sched_barrier(0);

    // ---- phase 1: A frags 4-7, stage B(kt+2), MFMA mi 4-7 ----
#pragma unroll
    for (int mi = 0; mi < 4; ++mi) {
      int row = wr * 128 + (mi + 4) * 16 + (l & 15);
      int kb = ((l >> 4) ^ ((row >> 1) & 3)) * 16;
      af[mi] = *(const i32x4*)&sA[cur][row * BK + kb];
    }
    if (pf) { stB(nxt, kt + 2, 0); stB(nxt, kt + 2, 1); }

    __builtin_amdgcn_s_barrier();
    asm volatile("s_waitcnt lgkmcnt(0)" ::: "memory");
    __builtin_amdgcn_sched_barrier(0);
    __builtin_amdgcn_s_setprio(1);
#pragma unroll
    for (int mi = 0; mi < 4; ++mi)
#pragma unroll
      for (int ni = 0; ni < 4; ++ni)
        acc[mi + 4][ni] = __builtin_amdgcn_mfma_i32_16x16x64_i8(
            af[mi], bfr[ni], acc[mi + 4][ni], 0, 0, 0);
    __builtin_amdgcn_s_setprio(0);
    __builtin_amdgcn_sched_barrier(0);

    if (kt + 1 < NT) {
      // retire tile kt+1's 4 loads; tile kt+2's 4 (if issued) stay in flight
      if (pf)
        asm volatile("s_waitcnt vmcnt(4)" ::: "memory");
      else
        asm volatile("s_waitcnt vmcnt(0)" ::: "memory");
      __builtin_amdgcn_s_barrier();
      __builtin_amdgcn_sched_barrier(0);
    }
    cur += 1; if (cur == 3) cur = 0;
  }

  // ---- epilogue: scale + bias on the fly (no fp32 array -> no spill) ----
  bool valid[4];
  float bb4[4];
#pragma unroll
  for (int ni = 0; ni < 4; ++ni) {
    int col = n0 + wc * 64 + ni * 16 + (l & 15);
    valid[ni] = (col < N_VOCAB);
    bb4[ni] = valid[ni] ? bq[col] : 0.f;
  }
#define LGT(mi, ni, r) ((float)acc[mi][ni][r] * scale + bb4[ni])

  __syncthreads();  // all LDS reads done before overlay writes
  float* redMax = (float*)&sA[0][0];  // [256][4]
  float* redSum = redMax + 1024;      // [256][4]

  float gm[8][4];
#pragma unroll
  for (int mi = 0; mi < 8; ++mi)
#pragma unroll
    for (int r = 0; r < 4; ++r) {
      float mval = -3.4e38f;
#pragma unroll
      for (int ni = 0; ni < 4; ++ni)
        if (valid[ni]) mval = fmaxf(mval, LGT(mi, ni, r));
#pragma unroll
      for (int off = 1; off < 16; off <<= 1)
        mval = fmaxf(mval, __shfl_xor(mval, off));
      if ((l & 15) == 0)
        redMax[(wr * 128 + mi * 16 + (l >> 4) * 4 + r) * 4 + wc] = mval;
    }
  __syncthreads();

#pragma unroll
  for (int mi = 0; mi < 8; ++mi)
#pragma unroll
    for (int r = 0; r < 4; ++r) {
      int rl = wr * 128 + mi * 16 + (l >> 4) * 4 + r;
      float gmax = fmaxf(fmaxf(redMax[rl * 4 + 0], redMax[rl * 4 + 1]),
                         fmaxf(redMax[rl * 4 + 2], redMax[rl * 4 + 3]));
      float s = 0.f;
#pragma unroll
      for (int ni = 0; ni < 4; ++ni)
        if (valid[ni]) s += __expf(LGT(mi, ni, r) - gmax);
#pragma unroll
      for (int off = 1; off < 16; off <<= 1)
        s += __shfl_xor(s, off);
      if ((l & 15) == 0) redSum[rl * 4 + wc] = s;
      gm[mi][r] = gmax;
    }
  __syncthreads();

  if (wc == 0 && (l & 15) == 0) {
#pragma unroll
    for (int mi = 0; mi < 8; ++mi)
#pragma unroll
      for (int r = 0; r < 4; ++r) {
        int rl = wr * 128 + mi * 16 + (l >> 4) * 4 + r;
        int rowg = m0 + rl;
        pmax[(size_t)rowg * NBC + nb] = gm[mi][r];
        psum[(size_t)rowg * NBC + nb] =
            (redSum[rl * 4 + 0] + redSum[rl * 4 + 1]) +
            (redSum[rl * 4 + 2] + redSum[rl * 4 + 3]);
      }
  }

  // ---- direct logit store, row-grouped ----
#pragma unroll
  for (int mi = 0; mi < 8; ++mi)
#pragma unroll
    for (int r = 0; r < 4; ++r) {
      int rowg = m0 + wr * 128 + mi * 16 + (l >> 4) * 4 + r;
      size_t rb = (size_t)rowg * N_VOCAB;
#pragma unroll
      for (int ni = 0; ni < 4; ++ni) {
        if (valid[ni]) {
          int col = n0 + wc * 64 + ni * 16 + (l & 15);
          outp[rb + col] = LGT(mi, ni, r);
        }
      }
    }
#undef LGT
}

// ---------------- merged: per-row logZ + subtract (one kernel) --------------
__global__ __launch_bounds__(256) void logz_sub_kernel(
    const float* __restrict__ pmax, const float* __restrict__ psum,
    float* __restrict__ out) {
  const int row = blockIdx.x;
  const float* pm = pmax + (size_t)row * NBC;
  const float* ps = psum + (size_t)row * NBC;
  const int tid = threadIdx.x;
  __shared__ float red[9];

  float m = -3.4e38f;
  for (int i = tid; i < NBC; i += 256) m = fmaxf(m, pm[i]);
#pragma unroll
  for (int off = 32; off; off >>= 1) m = fmaxf(m, __shfl_xor(m, off));
  if ((tid & 63) == 0) red[tid >> 6] = m;
  __syncthreads();
  m = fmaxf(fmaxf(red[0], red[1]), fmaxf(red[2], red[3]));

  float s = 0.f;
  for (int i = tid; i < NBC; i += 256) s += ps[i] * __expf(pm[i] - m);
#pragma unroll
  for (int off = 32; off; off >>= 1) s += __shfl_xor(s, off);
  if ((tid & 63) == 0) red[4 + (tid >> 6)] = s;
  __syncthreads();
  if (tid == 0) {
    s = red[4] + red[5] + red[6] + red[7];
    red[8] = m + __logf(s);
  }
  __syncthreads();
  const float lz = red[8];

  const size_t base = (size_t)row * N_VOCAB;
  const int a = (4 - (row & 3)) & 3;  // base mod 4 floats == row mod 4
  if (tid < a) out[base + tid] -= lz;
  const int n4 = (N_VOCAB - a) >> 2;
  float4* p = (float4*)(out + base + a);
  for (int i = tid; i < n4; i += 256) {
    float4 v = p[i];
    v.x -= lz; v.y -= lz; v.z -= lz; v.w -= lz;
    p[i] = v;
  }
  const int done = a + n4 * 4;
  if (tid < N_VOCAB - done) out[base + done + tid] -= lz;
}

extern "C" void kernel_launch(void* const* d_in, const int* in_sizes, int n_in,
                              void* d_out, int out_size, void* d_ws,
                              size_t ws_size, hipStream_t stream) {
  const float* x = (const float*)d_in[0];
  const float* W = (const float*)d_in[1];
  const float* b = (const float*)d_in[2];
  float* out = (float*)d_out;

  char* ws = (char*)d_ws;
  unsigned* amax = (unsigned*)ws;                       // 8 B
  float* bq = (float*)(ws + 4096);                      // 202 KB
  float* pmax = (float*)(ws + (2ull << 20));            // 1.62 MB
  float* psum = (float*)(ws + (6ull << 20));            // 1.62 MB
  signed char* qx = (signed char*)(ws + (10ull << 20)); // 2 MB
  signed char* qw = (signed char*)(ws + (14ull << 20)); // 51.6 MB

  hipMemsetAsync(amax, 0, 8, stream);

  const int nx4 = (M_ROWS * D_K) / 4;   // 524288
  const int nw4 = (N_VOCAB * D_K) / 4;  // 12865792

  absmax2_kernel<<<2560, 256, 0, stream>>>((const float4*)x, nx4,
                                           (const float4*)W, nw4, amax);

  quant_kernel<<<2048 + 50432 + 197, 256, 0, stream>>>(
      (const float4*)x, (const float4*)W, b, (char4*)qx, (char4*)qw, bq, amax);

  gemm_kernel<<<GEMM_BLOCKS, 512, 0, stream>>>(qx, qw, bq, amax, out, pmax,
                                               psum);

  logz_sub_kernel<<<M_ROWS, 256, 0, stream>>>(pmax, psum, out);
}